// Round 18
// baseline (279.882 us; speedup 1.0000x reference)
//
#include <hip/hip_runtime.h>
#include <hip/hip_fp16.h>

#define L_TOT 65536

// ws float offsets
#define WS_UG   0        // [4][128][8]
#define WS_VG   4096     // [4][128][8]
#define WS_A    8192     // [4][128]
#define WS_GB1  8704     // [4][128]
#define WS_WHP  12288    // uint[128][32]: Wh bf16 pairs (unfolded, shared)
#define WS_WLP  16384    // uint[128][32]: Wl residual bf16 pairs
#define WS_CGP  32768    // uint[4][64][64]: packed f16 pairs of Cg

typedef __attribute__((ext_vector_type(8))) short short8;
typedef __attribute__((ext_vector_type(4))) float f32x4;
typedef _Float16 half8 __attribute__((ext_vector_type(8)));

__device__ __forceinline__ unsigned bf16rne(float f) {
    unsigned u = __builtin_bit_cast(unsigned, f);
    return (u + 0x7fffu + ((u >> 16) & 1u)) >> 16;
}
__device__ __forceinline__ float bfhi(unsigned u) {
    return __builtin_bit_cast(float, u << 16);
}
__device__ __forceinline__ unsigned f16pk(float a, float b) {
    __half2 h = __floats2half2_rn(a, b);
    return __builtin_bit_cast(unsigned, h);
}

__global__ __launch_bounds__(128) void mod_kernel(
    const float* __restrict__ g, const float* __restrict__ in_proj_w,
    const float* __restrict__ U_base, const float* __restrict__ V_base,
    const float* __restrict__ a_base, const float* __restrict__ out_proj_w,
    const float* __restrict__ mod_uv_w, const float* __restrict__ mod_uv_b,
    const float* __restrict__ mod_a_w, const float* __restrict__ mod_a_b,
    const float* __restrict__ mod_B_w, const float* __restrict__ mod_B_b,
    const float* __restrict__ mod_C_w, const float* __restrict__ mod_C_b,
    float* __restrict__ ws)
{
    __shared__ float gsh[64];
    __shared__ float uvs[16];
    __shared__ float gCs[64];
    const int b = blockIdx.x, tid = threadIdx.x;
    if (tid < 64) gsh[tid] = g[b * 64 + tid];
    __syncthreads();
    if (tid < 16) {
        float s = mod_uv_b[tid];
        for (int d = 0; d < 64; ++d) s += mod_uv_w[tid * 64 + d] * gsh[d];
        uvs[tid] = fminf(0.5f, fmaxf(-0.5f, s));
    }
    float ga_v, gB_v;
    {
        float s = mod_a_b[tid];
        for (int d = 0; d < 64; ++d) s += mod_a_w[tid * 64 + d] * gsh[d];
        ga_v = fminf(2.0f, fmaxf(-2.0f, s));
    }
    {
        float s = mod_B_b[tid];
        for (int d = 0; d < 64; ++d) s += mod_B_w[tid * 64 + d] * gsh[d];
        gB_v = 1.0f + fminf(1.0f, fmaxf(-1.0f, s));
    }
    if (tid < 64) {
        float s = mod_C_b[tid];
        for (int d = 0; d < 64; ++d) s += mod_C_w[tid * 64 + d] * gsh[d];
        gCs[tid] = 1.0f + fminf(0.5f, fmaxf(-0.5f, s));
    }
    __syncthreads();
    for (int idx = tid; idx < 1024; idx += 128) {
        int m = idx >> 3, r = idx & 7;
        ws[WS_UG + (b * 128 + m) * 8 + r] = U_base[m * 8 + r] * (1.0f + uvs[r]);
        ws[WS_VG + (b * 128 + m) * 8 + r] = V_base[m * 8 + r] * (1.0f + uvs[8 + r]);
    }
    ws[WS_A   + b * 128 + tid] = a_base[tid] + ga_v;
    ws[WS_GB1 + b * 128 + tid] = gB_v;
    unsigned* CgP = (unsigned*)(ws + WS_CGP);
    for (int idx = tid; idx < 4096; idx += 128) {
        int c = idx >> 6, j = idx & 63;
        float s = gCs[c];
        float c0 = out_proj_w[c * 128 + 2 * j]     * s;
        float c1 = out_proj_w[c * 128 + 2 * j + 1] * s;
        CgP[(b * 64 + c) * 64 + j] = f16pk(c0, c1);
    }
    // Unfolded W packer (r13-exact; lo = even k), shared across b
    if (b == 0) {
        unsigned* WhP = (unsigned*)(ws + WS_WHP);
        unsigned* WlP = (unsigned*)(ws + WS_WLP);
        for (int idx = tid; idx < 4096; idx += 128) {
            int m = idx >> 5, j = idx & 31;
            float w0 = in_proj_w[m * 64 + 2 * j];
            float w1 = in_proj_w[m * 64 + 2 * j + 1];
            unsigned u0 = bf16rne(w0), u1 = bf16rne(w1);
            WhP[idx] = u0 | (u1 << 16);
            float r0 = w0 - bfhi(u0);
            float r1 = w1 - bfhi(u1);
            WlP[idx] = bf16rne(r0) | (bf16rne(r1) << 16);
        }
    }
}

// Fused scan, r16-bit-exact numerics. Per segment: gemm_load(s+1) [global x
// -> regs, issued early], scan_seg(s) [r16 butterfly, covers load latency],
// gemm_compute(s+1) [r13-exact 3-chain MFMA -> LDS xp dbuf], y_burst(s).
__global__ __launch_bounds__(64, 1) void scan_kernel(
    const float* __restrict__ x, const float* __restrict__ ws,
    const unsigned* __restrict__ WhP, const unsigned* __restrict__ WlP,
    const float* __restrict__ bias, const unsigned* __restrict__ CgP,
    const float* __restrict__ h0, float* __restrict__ out)
{
    __shared__ __align__(16) unsigned xp[2][16 * 68];   // [l][mp]
    __shared__ __align__(16) unsigned Hs[16 * 68];
    const int lane = threadIdx.x;
    const int bb = blockIdx.x >> 7, k = blockIdx.x & 127;
    const int m0 = 2 * lane;
    const int lp = lane & 7;
    const int row16 = lane & 15, grp = lane >> 4;

    float VgP0[8], VgP1[8], U0x[8], U1x[8];
    {
        const float* vg = ws + WS_VG + (bb * 128 + m0) * 8;
        const float* ug = ws + WS_UG + (bb * 128 + m0) * 8;
        #pragma unroll
        for (int j = 0; j < 8; ++j) {
            int r = j ^ lp;
            VgP0[j] = vg[r];     VgP1[j] = vg[8 + r];
            U0x[j]  = ug[r];     U1x[j]  = ug[8 + r];
        }
    }
    const float a0 = ws[WS_A + bb * 128 + m0];
    const float a1 = ws[WS_A + bb * 128 + m0 + 1];
    float ha = h0[m0], hb = h0[m0 + 1];

    // y A-fragments in registers (r16 style)
    half8 Af[4][4];
    #pragma unroll
    for (int ct = 0; ct < 4; ++ct)
        #pragma unroll
        for (int kc = 0; kc < 4; ++kc) {
            const unsigned* p = CgP + (bb * 64 + ct * 16 + row16) * 64 + kc * 16 + grp * 4;
            Af[ct][kc] = __builtin_bit_cast(half8, *(const uint4*)p);
        }

    const float* xgb = x + (size_t)(bb * 64) * L_TOT + (size_t)k * 512 + row16;
    float* ob[4];
    #pragma unroll
    for (int ct = 0; ct < 4; ++ct)
        ob[ct] = out + (size_t)(bb * 64 + ct * 16 + grp * 4) * L_TOT + k * 512 + row16;

    const float fz = 0.0f;
    float xf[16];

    // ---- issue global x loads for segment s ----
    auto gemm_load = [&](int s) {
        const float* xs_ = xgb + s * 16;
        #pragma unroll
        for (int kc = 0; kc < 2; ++kc)
            #pragma unroll
            for (int q = 0; q < 4; ++q) {
                int c = kc * 32 + grp * 8 + 2 * q;
                xf[kc * 8 + 2 * q]     = xs_[(size_t)c * L_TOT];
                xf[kc * 8 + 2 * q + 1] = xs_[(size_t)(c + 1) * L_TOT];
            }
    };

    // ---- 3-chain MFMA x_proj (r13-exact) -> xp[s&1] ----
    auto gemm_compute = [&](int s) {
        unsigned* xpd = xp[s & 1];
        short8 Bh[2], Bl[2];
        #pragma unroll
        for (int kc = 0; kc < 2; ++kc) {
            unsigned uh[4], ul[4];
            #pragma unroll
            for (int q = 0; q < 4; ++q) {
                float f0 = xf[kc * 8 + 2 * q], f1 = xf[kc * 8 + 2 * q + 1];
                unsigned u0 = bf16rne(f0), u1 = bf16rne(f1);
                uh[q] = u0 | (u1 << 16);
                float r0 = f0 - bfhi(u0);
                float r1 = f1 - bfhi(u1);
                ul[q] = bf16rne(r0) | (bf16rne(r1) << 16);
            }
            uint4 th = {uh[0], uh[1], uh[2], uh[3]};
            uint4 tl = {ul[0], ul[1], ul[2], ul[3]};
            Bh[kc] = __builtin_bit_cast(short8, th);
            Bl[kc] = __builtin_bit_cast(short8, tl);
        }
        #pragma unroll
        for (int mt = 0; mt < 8; ++mt) {
            const int mrow = mt * 16 + row16;
            short8 Ah0 = __builtin_bit_cast(short8, *(const uint4*)(WhP + mrow * 32 + grp * 4));
            short8 Ah1 = __builtin_bit_cast(short8, *(const uint4*)(WhP + mrow * 32 + 16 + grp * 4));
            short8 Al0 = __builtin_bit_cast(short8, *(const uint4*)(WlP + mrow * 32 + grp * 4));
            short8 Al1 = __builtin_bit_cast(short8, *(const uint4*)(WlP + mrow * 32 + 16 + grp * 4));
            f32x4 acc = {0.f, 0.f, 0.f, 0.f};
            acc = __builtin_amdgcn_mfma_f32_16x16x32_bf16(Ah0, Bh[0], acc, 0, 0, 0);
            acc = __builtin_amdgcn_mfma_f32_16x16x32_bf16(Ah1, Bh[1], acc, 0, 0, 0);
            acc = __builtin_amdgcn_mfma_f32_16x16x32_bf16(Ah0, Bl[0], acc, 0, 0, 0);
            acc = __builtin_amdgcn_mfma_f32_16x16x32_bf16(Ah1, Bl[1], acc, 0, 0, 0);
            acc = __builtin_amdgcn_mfma_f32_16x16x32_bf16(Al0, Bh[0], acc, 0, 0, 0);
            acc = __builtin_amdgcn_mfma_f32_16x16x32_bf16(Al1, Bh[1], acc, 0, 0, 0);
            const int mb = mt * 16 + 4 * grp;
            float4 bi = *(const float4*)(bias + mb);
            float4 gb = *(const float4*)(ws + WS_GB1 + bb * 128 + mb);
            float v0 = (acc[0] + bi.x) * gb.x;
            float v1 = (acc[1] + bi.y) * gb.y;
            float v2 = (acc[2] + bi.z) * gb.z;
            float v3 = (acc[3] + bi.w) * gb.w;
            const int mp = mt * 8 + grp * 2;
            xpd[row16 * 68 + mp]     = f16pk(v0, v1);
            xpd[row16 * 68 + mp + 1] = f16pk(v2, v3);
        }
    };

    // ---- 16 recurrence steps (r16-exact) ----
    auto scan_seg = [&](int s) {
        const unsigned* xpk = xp[s & 1];
        unsigned xcur = xpk[lane];
        #pragma unroll
        for (int i = 0; i < 16; ++i) {
            unsigned xnxt = (i < 15) ? xpk[(i + 1) * 68 + lane] : 0u;
            const float2 xv = __half22float2(__builtin_bit_cast(__half2, xcur));
            float p0 = fmaf(VgP1[0], hb, VgP0[0] * ha);
            float p1 = fmaf(VgP1[1], hb, VgP0[1] * ha);
            float p2 = fmaf(VgP1[2], hb, VgP0[2] * ha);
            float p3 = fmaf(VgP1[3], hb, VgP0[3] * ha);
            float p4 = fmaf(VgP1[4], hb, VgP0[4] * ha);
            float p5 = fmaf(VgP1[5], hb, VgP0[5] * ha);
            float p6 = fmaf(VgP1[6], hb, VgP0[6] * ha);
            float p7 = fmaf(VgP1[7], hb, VgP0[7] * ha);
            asm volatile(
                "s_nop 1\n\t"
                "v_add_f32_dpp %0, %1, %0 quad_perm:[1,0,3,2] row_mask:0xf bank_mask:0xf bound_ctrl:1\n\t"
                "v_add_f32_dpp %2, %3, %2 quad_perm:[1,0,3,2] row_mask:0xf bank_mask:0xf bound_ctrl:1\n\t"
                "v_add_f32_dpp %5, %4, %5 quad_perm:[1,0,3,2] row_mask:0xf bank_mask:0xf bound_ctrl:1\n\t"
                "v_add_f32_dpp %7, %6, %7 quad_perm:[1,0,3,2] row_mask:0xf bank_mask:0xf bound_ctrl:1\n\t"
                "s_nop 1\n\t"
                "v_add_f32_dpp %0, %2, %0 quad_perm:[2,3,0,1] row_mask:0xf bank_mask:0xf bound_ctrl:1\n\t"
                "v_add_f32_dpp %7, %5, %7 quad_perm:[2,3,0,1] row_mask:0xf bank_mask:0xf bound_ctrl:1\n\t"
                "s_nop 1\n\t"
                "v_add_f32_dpp %0, %7, %0 row_half_mirror row_mask:0xf bank_mask:0xf bound_ctrl:1\n\t"
                : "+v"(p0), "+v"(p1), "+v"(p2), "+v"(p3),
                  "+v"(p4), "+v"(p5), "+v"(p6), "+v"(p7));
            p0 += __builtin_bit_cast(float, __builtin_amdgcn_ds_swizzle(
                      __builtin_bit_cast(int, p0), 0x201F));
            p0 += __builtin_bit_cast(float, __builtin_amdgcn_ds_swizzle(
                      __builtin_bit_cast(int, p0), 0x401F));
            p0 += __shfl_xor(p0, 32);
            float vr1, vr2, vr3, vr4, vr5, vr6, vr7;
            asm volatile(
                "s_nop 1\n\t"
                "v_add_f32_dpp %0, %7, %8 quad_perm:[1,0,3,2] row_mask:0xf bank_mask:0xf bound_ctrl:1\n\t"
                "v_add_f32_dpp %1, %7, %8 quad_perm:[2,3,0,1] row_mask:0xf bank_mask:0xf bound_ctrl:1\n\t"
                "v_add_f32_dpp %2, %7, %8 quad_perm:[3,2,1,0] row_mask:0xf bank_mask:0xf bound_ctrl:1\n\t"
                "v_add_f32_dpp %6, %7, %8 row_half_mirror row_mask:0xf bank_mask:0xf bound_ctrl:1\n\t"
                "s_nop 1\n\t"
                "v_add_f32_dpp %5, %6, %8 quad_perm:[1,0,3,2] row_mask:0xf bank_mask:0xf bound_ctrl:1\n\t"
                "v_add_f32_dpp %4, %6, %8 quad_perm:[2,3,0,1] row_mask:0xf bank_mask:0xf bound_ctrl:1\n\t"
                "v_add_f32_dpp %3, %6, %8 quad_perm:[3,2,1,0] row_mask:0xf bank_mask:0xf bound_ctrl:1\n\t"
                : "=&v"(vr1), "=&v"(vr2), "=&v"(vr3), "=&v"(vr4),
                  "=&v"(vr5), "=&v"(vr6), "=&v"(vr7)
                : "v"(p0), "v"(fz));
            float c0 = fmaf(vr1, U0x[1], p0 * U0x[0]);
            c0 = fmaf(vr2, U0x[2], c0);
            c0 = fmaf(vr3, U0x[3], c0);
            float c1 = vr4 * U0x[4];
            c1 = fmaf(vr5, U0x[5], c1);
            c1 = fmaf(vr6, U0x[6], c1);
            c1 = fmaf(vr7, U0x[7], c1);
            float av0 = c0 + c1;
            float d0 = fmaf(vr1, U1x[1], p0 * U1x[0]);
            d0 = fmaf(vr2, U1x[2], d0);
            d0 = fmaf(vr3, U1x[3], d0);
            float d1 = vr4 * U1x[4];
            d1 = fmaf(vr5, U1x[5], d1);
            d1 = fmaf(vr6, U1x[6], d1);
            d1 = fmaf(vr7, U1x[7], d1);
            float av1 = d0 + d1;
            ha = fminf(10.0f, fmaxf(-10.0f, fmaf(a0, ha, av0) + xv.x));
            hb = fminf(10.0f, fmaxf(-10.0f, fmaf(a1, hb, av1) + xv.y));
            Hs[i * 68 + lane] = f16pk(ha, hb);
            xcur = xnxt;
        }
    };

    // ---- y-burst (r16-exact) ----
    auto y_burst = [&](int s) {
        half8 Bf[4];
        #pragma unroll
        for (int kc = 0; kc < 4; ++kc)
            Bf[kc] = __builtin_bit_cast(half8,
                *(const uint4*)&Hs[row16 * 68 + kc * 16 + grp * 4]);
        #pragma unroll
        for (int ct = 0; ct < 4; ++ct) {
            f32x4 acc = {0.0f, 0.0f, 0.0f, 0.0f};
            #pragma unroll
            for (int kc = 0; kc < 4; ++kc)
                acc = __builtin_amdgcn_mfma_f32_16x16x32_f16(Af[ct][kc], Bf[kc], acc, 0, 0, 0);
            #pragma unroll
            for (int r = 0; r < 4; ++r) {
                float y = fminf(10.0f, fmaxf(-10.0f, acc[r]));
                ob[ct][(size_t)r * L_TOT + s * 16] = y;
            }
        }
    };

    gemm_load(0);
    gemm_compute(0);
    #pragma unroll 1
    for (int s = 0; s < 32; ++s) {
        if (s < 31) gemm_load(s + 1);     // HBM latency hides under scan_seg
        scan_seg(s);
        if (s < 31) gemm_compute(s + 1);
        y_burst(s);
    }
}

extern "C" void kernel_launch(void* const* d_in, const int* in_sizes, int n_in,
                              void* d_out, int out_size, void* d_ws, size_t ws_size,
                              hipStream_t stream) {
    const float* x          = (const float*)d_in[0];
    const float* g          = (const float*)d_in[1];
    const float* in_proj_w  = (const float*)d_in[2];
    const float* in_proj_b  = (const float*)d_in[3];
    const float* out_proj_w = (const float*)d_in[4];
    const float* U_base     = (const float*)d_in[5];
    const float* V_base     = (const float*)d_in[6];
    const float* a_base     = (const float*)d_in[7];
    const float* mod_uv_w   = (const float*)d_in[8];
    const float* mod_uv_b   = (const float*)d_in[9];
    const float* mod_a_w    = (const float*)d_in[10];
    const float* mod_a_b    = (const float*)d_in[11];
    const float* mod_B_w    = (const float*)d_in[12];
    const float* mod_B_b    = (const float*)d_in[13];
    const float* mod_C_w    = (const float*)d_in[14];
    const float* mod_C_b    = (const float*)d_in[15];
    const float* h0         = (const float*)d_in[16];
    float* out = (float*)d_out;
    float* ws  = (float*)d_ws;

    hipLaunchKernelGGL(mod_kernel, dim3(4), dim3(128), 0, stream,
                       g, in_proj_w, U_base, V_base, a_base, out_proj_w,
                       mod_uv_w, mod_uv_b, mod_a_w, mod_a_b,
                       mod_B_w, mod_B_b, mod_C_w, mod_C_b, ws);
    hipLaunchKernelGGL(scan_kernel, dim3(512), dim3(64), 0, stream,
                       x, ws, (const unsigned*)(ws + WS_WHP), (const unsigned*)(ws + WS_WLP),
                       in_proj_b, (const unsigned*)(ws + WS_CGP), h0, out);
}

// Round 19
// 154.596 us; speedup vs baseline: 1.8104x; 1.8104x over previous
//
#include <hip/hip_runtime.h>
#include <hip/hip_fp16.h>

#define L_TOT 65536

// ws float offsets
#define WS_UG   0        // [4][128][8]
#define WS_VG   4096     // [4][128][8]
#define WS_A    8192     // [4][128]
#define WS_GB1  8704     // [4][128]
#define WS_WHP  12288    // uint[128][32]: Wh bf16 pairs
#define WS_WLP  16384    // uint[128][32]: Wl residual bf16 pairs
#define WS_CGP  32768    // uint[4][64][64]: packed f16 pairs of Cg
#define WS_XS   65536    // uint[4][65536][64]: packed fp16 m-pairs of x_seq

typedef __attribute__((ext_vector_type(8))) short short8;
typedef __attribute__((ext_vector_type(4))) float f32x4;
typedef _Float16 half8 __attribute__((ext_vector_type(8)));

__device__ __forceinline__ unsigned bf16rne(float f) {
    unsigned u = __builtin_bit_cast(unsigned, f);
    return (u + 0x7fffu + ((u >> 16) & 1u)) >> 16;
}
__device__ __forceinline__ float bfhi(unsigned u) {
    return __builtin_bit_cast(float, u << 16);
}
__device__ __forceinline__ unsigned f16pk(float a, float b) {
    __half2 h = __floats2half2_rn(a, b);
    return __builtin_bit_cast(unsigned, h);
}

__global__ __launch_bounds__(128) void mod_kernel(
    const float* __restrict__ g, const float* __restrict__ in_proj_w,
    const float* __restrict__ U_base, const float* __restrict__ V_base,
    const float* __restrict__ a_base, const float* __restrict__ out_proj_w,
    const float* __restrict__ mod_uv_w, const float* __restrict__ mod_uv_b,
    const float* __restrict__ mod_a_w, const float* __restrict__ mod_a_b,
    const float* __restrict__ mod_B_w, const float* __restrict__ mod_B_b,
    const float* __restrict__ mod_C_w, const float* __restrict__ mod_C_b,
    float* __restrict__ ws)
{
    __shared__ float gsh[64];
    __shared__ float uvs[16];
    __shared__ float gCs[64];
    const int b = blockIdx.x, tid = threadIdx.x;
    if (tid < 64) gsh[tid] = g[b * 64 + tid];
    __syncthreads();
    if (tid < 16) {
        float s = mod_uv_b[tid];
        for (int d = 0; d < 64; ++d) s += mod_uv_w[tid * 64 + d] * gsh[d];
        uvs[tid] = fminf(0.5f, fmaxf(-0.5f, s));
    }
    float ga_v, gB_v;
    {
        float s = mod_a_b[tid];
        for (int d = 0; d < 64; ++d) s += mod_a_w[tid * 64 + d] * gsh[d];
        ga_v = fminf(2.0f, fmaxf(-2.0f, s));
    }
    {
        float s = mod_B_b[tid];
        for (int d = 0; d < 64; ++d) s += mod_B_w[tid * 64 + d] * gsh[d];
        gB_v = 1.0f + fminf(1.0f, fmaxf(-1.0f, s));
    }
    if (tid < 64) {
        float s = mod_C_b[tid];
        for (int d = 0; d < 64; ++d) s += mod_C_w[tid * 64 + d] * gsh[d];
        gCs[tid] = 1.0f + fminf(0.5f, fmaxf(-0.5f, s));
    }
    __syncthreads();
    for (int idx = tid; idx < 1024; idx += 128) {
        int m = idx >> 3, r = idx & 7;
        ws[WS_UG + (b * 128 + m) * 8 + r] = U_base[m * 8 + r] * (1.0f + uvs[r]);
        ws[WS_VG + (b * 128 + m) * 8 + r] = V_base[m * 8 + r] * (1.0f + uvs[8 + r]);
    }
    ws[WS_A   + b * 128 + tid] = a_base[tid] + ga_v;
    ws[WS_GB1 + b * 128 + tid] = gB_v;
    unsigned* CgP = (unsigned*)(ws + WS_CGP);
    for (int idx = tid; idx < 4096; idx += 128) {
        int c = idx >> 6, j = idx & 63;
        float s = gCs[c];
        float c0 = out_proj_w[c * 128 + 2 * j]     * s;
        float c1 = out_proj_w[c * 128 + 2 * j + 1] * s;
        CgP[(b * 64 + c) * 64 + j] = f16pk(c0, c1);
    }
    if (b == 0) {
        unsigned* WhP = (unsigned*)(ws + WS_WHP);
        unsigned* WlP = (unsigned*)(ws + WS_WLP);
        for (int idx = tid; idx < 4096; idx += 128) {
            int m = idx >> 5, j = idx & 31;
            float w0 = in_proj_w[m * 64 + 2 * j];
            float w1 = in_proj_w[m * 64 + 2 * j + 1];
            unsigned u0 = bf16rne(w0), u1 = bf16rne(w1);
            WhP[idx] = u0 | (u1 << 16);
            float r0 = w0 - bfhi(u0);
            float r1 = w1 - bfhi(u1);
            WlP[idx] = bf16rne(r0) | (bf16rne(r1) << 16);
        }
    }
}

// MFMA in_proj (r13/r16-proven, unchanged).
__global__ __launch_bounds__(256) void inproj_mfma(
    const float* __restrict__ x, const unsigned* __restrict__ WhP,
    const unsigned* __restrict__ WlP, const float* __restrict__ bias,
    const float* __restrict__ ws, unsigned* __restrict__ xs16)
{
    __shared__ __align__(16) unsigned XhS[64 * 36];
    __shared__ __align__(16) unsigned XlS[64 * 36];
    const int tid = threadIdx.x;
    const int b = blockIdx.y;
    const int l0 = blockIdx.x * 64;

    {
        const int l_st = tid & 63, cpg = tid >> 6;
        #pragma unroll
        for (int s = 0; s < 8; ++s) {
            int cp = cpg * 8 + s;
            float x0 = x[(size_t)(b * 64 + 2 * cp) * L_TOT + l0 + l_st];
            float x1 = x[(size_t)(b * 64 + 2 * cp + 1) * L_TOT + l0 + l_st];
            unsigned u0 = bf16rne(x0), u1 = bf16rne(x1);
            XhS[l_st * 36 + cp] = u0 | (u1 << 16);
            float r0 = x0 - bfhi(u0);
            float r1 = x1 - bfhi(u1);
            XlS[l_st * 36 + cp] = bf16rne(r0) | (bf16rne(r1) << 16);
        }
    }
    const int lane = tid & 63, wv = tid >> 6;
    const int row16 = lane & 15, grp = lane >> 4;

    short8 Ah[2][2], Al[2][2];
    #pragma unroll
    for (int t = 0; t < 2; ++t) {
        const int mrow = (2 * wv + t) * 16 + row16;
        #pragma unroll
        for (int kc = 0; kc < 2; ++kc) {
            Ah[t][kc] = __builtin_bit_cast(short8,
                *(const uint4*)(WhP + mrow * 32 + kc * 16 + grp * 4));
            Al[t][kc] = __builtin_bit_cast(short8,
                *(const uint4*)(WlP + mrow * 32 + kc * 16 + grp * 4));
        }
    }
    __syncthreads();

    #pragma unroll
    for (int ti = 0; ti < 4; ++ti) {
        const int lcol = ti * 16 + row16;
        short8 Bh[2], Bl[2];
        #pragma unroll
        for (int kc = 0; kc < 2; ++kc) {
            Bh[kc] = __builtin_bit_cast(short8,
                *(const uint4*)&XhS[lcol * 36 + kc * 16 + grp * 4]);
            Bl[kc] = __builtin_bit_cast(short8,
                *(const uint4*)&XlS[lcol * 36 + kc * 16 + grp * 4]);
        }
        #pragma unroll
        for (int t = 0; t < 2; ++t) {
            f32x4 acc = {0.f, 0.f, 0.f, 0.f};
            acc = __builtin_amdgcn_mfma_f32_16x16x32_bf16(Ah[t][0], Bh[0], acc, 0, 0, 0);
            acc = __builtin_amdgcn_mfma_f32_16x16x32_bf16(Ah[t][1], Bh[1], acc, 0, 0, 0);
            acc = __builtin_amdgcn_mfma_f32_16x16x32_bf16(Ah[t][0], Bl[0], acc, 0, 0, 0);
            acc = __builtin_amdgcn_mfma_f32_16x16x32_bf16(Ah[t][1], Bl[1], acc, 0, 0, 0);
            acc = __builtin_amdgcn_mfma_f32_16x16x32_bf16(Al[t][0], Bh[0], acc, 0, 0, 0);
            acc = __builtin_amdgcn_mfma_f32_16x16x32_bf16(Al[t][1], Bh[1], acc, 0, 0, 0);
            const int mb = (2 * wv + t) * 16 + 4 * grp;
            const int l = l0 + lcol;
            float4 bi = *(const float4*)(bias + mb);
            float4 gb = *(const float4*)(ws + WS_GB1 + b * 128 + mb);
            float v0 = (acc[0] + bi.x) * gb.x;
            float v1 = (acc[1] + bi.y) * gb.y;
            float v2 = (acc[2] + bi.z) * gb.z;
            float v3 = (acc[3] + bi.w) * gb.w;
            uint2 pk = {f16pk(v0, v1), f16pk(v2, v3)};
            *(uint2*)(xs16 + ((size_t)b * L_TOT + l) * 64 + (mb >> 1)) = pk;
        }
    }
}

// One WAVE per (b, chunk). r16 butterfly reduce, but ALL cross-lane ops are
// VALU-class: xor8 = row_ror:8 DPP, xor16 = v_permlane16_swap_b32,
// xor32 = v_permlane32_swap_b32. Addend values/order identical to r16
// (commutativity) -> bit-identical results.
__global__ __launch_bounds__(64, 1) void scan_kernel(
    const unsigned* __restrict__ xs16, const float* __restrict__ ws,
    const unsigned* __restrict__ CgP, const float* __restrict__ h0,
    float* __restrict__ out)
{
    __shared__ __align__(16) unsigned Hs[16 * 68];
    const int lane = threadIdx.x;
    const int bb = blockIdx.x >> 7, k = blockIdx.x & 127;
    const int m0 = 2 * lane;
    const int lp = lane & 7;
    const int row16 = lane & 15, grp = lane >> 4;

    float VgP0[8], VgP1[8], U0x[8], U1x[8];
    {
        const float* vg = ws + WS_VG + (bb * 128 + m0) * 8;
        const float* ug = ws + WS_UG + (bb * 128 + m0) * 8;
        #pragma unroll
        for (int j = 0; j < 8; ++j) {
            int r = j ^ lp;
            VgP0[j] = vg[r];     VgP1[j] = vg[8 + r];
            U0x[j]  = ug[r];     U1x[j]  = ug[8 + r];
        }
    }
    const float a0 = ws[WS_A + bb * 128 + m0];
    const float a1 = ws[WS_A + bb * 128 + m0 + 1];
    float ha = h0[m0], hb = h0[m0 + 1];

    half8 Af[4][4];
    #pragma unroll
    for (int ct = 0; ct < 4; ++ct)
        #pragma unroll
        for (int kc = 0; kc < 4; ++kc) {
            const unsigned* p = CgP + (bb * 64 + ct * 16 + row16) * 64 + kc * 16 + grp * 4;
            Af[ct][kc] = __builtin_bit_cast(half8, *(const uint4*)p);
        }

    const unsigned* xsp = xs16 + ((size_t)bb * L_TOT + (size_t)k * 512) * 64 + lane;
    float* ob[4];
    #pragma unroll
    for (int ct = 0; ct < 4; ++ct)
        ob[ct] = out + (size_t)(bb * 64 + ct * 16 + grp * 4) * L_TOT + k * 512 + row16;

    unsigned xqA[16], xqB[16];
    auto prefetch = [&](unsigned (&xq)[16], int seg) {
        const unsigned* xb = xsp + (size_t)seg * 1024;
        #pragma unroll
        for (int i = 0; i < 16; ++i) xq[i] = xb[(size_t)i * 64];
    };

    const float fz = 0.0f;

    auto do_seg = [&](const unsigned (&xq)[16], int t16) {
        #pragma unroll
        for (int i = 0; i < 16; ++i) {
            const float2 xv = __half22float2(__builtin_bit_cast(__half2, xq[i]));
            float p0 = fmaf(VgP1[0], hb, VgP0[0] * ha);
            float p1 = fmaf(VgP1[1], hb, VgP0[1] * ha);
            float p2 = fmaf(VgP1[2], hb, VgP0[2] * ha);
            float p3 = fmaf(VgP1[3], hb, VgP0[3] * ha);
            float p4 = fmaf(VgP1[4], hb, VgP0[4] * ha);
            float p5 = fmaf(VgP1[5], hb, VgP0[5] * ha);
            float p6 = fmaf(VgP1[6], hb, VgP0[6] * ha);
            float p7 = fmaf(VgP1[7], hb, VgP0[7] * ha);
            // reduce-scatter within 8-lane groups + xor8 via row_ror:8 (all DPP)
            asm volatile(
                "s_nop 1\n\t"
                "v_add_f32_dpp %0, %1, %0 quad_perm:[1,0,3,2] row_mask:0xf bank_mask:0xf bound_ctrl:1\n\t"
                "v_add_f32_dpp %2, %3, %2 quad_perm:[1,0,3,2] row_mask:0xf bank_mask:0xf bound_ctrl:1\n\t"
                "v_add_f32_dpp %5, %4, %5 quad_perm:[1,0,3,2] row_mask:0xf bank_mask:0xf bound_ctrl:1\n\t"
                "v_add_f32_dpp %7, %6, %7 quad_perm:[1,0,3,2] row_mask:0xf bank_mask:0xf bound_ctrl:1\n\t"
                "s_nop 1\n\t"
                "v_add_f32_dpp %0, %2, %0 quad_perm:[2,3,0,1] row_mask:0xf bank_mask:0xf bound_ctrl:1\n\t"
                "v_add_f32_dpp %7, %5, %7 quad_perm:[2,3,0,1] row_mask:0xf bank_mask:0xf bound_ctrl:1\n\t"
                "s_nop 1\n\t"
                "v_add_f32_dpp %0, %7, %0 row_half_mirror row_mask:0xf bank_mask:0xf bound_ctrl:1\n\t"
                "s_nop 1\n\t"
                "v_add_f32_dpp %0, %0, %0 row_ror:8 row_mask:0xf bank_mask:0xf bound_ctrl:1\n\t"
                : "+v"(p0), "+v"(p1), "+v"(p2), "+v"(p3),
                  "+v"(p4), "+v"(p5), "+v"(p6), "+v"(p7));
            // xor16 via permlane16_swap (VALU), xor32 via permlane32_swap
            {
                float b16 = p0;
                asm volatile("s_nop 1\n\tv_permlane16_swap_b32 %0, %1"
                             : "+v"(p0), "+v"(b16));
                p0 = p0 + b16;
                float b32 = p0;
                asm volatile("s_nop 1\n\tv_permlane32_swap_b32 %0, %1"
                             : "+v"(p0), "+v"(b32));
                p0 = p0 + b32;
            }
            // allgather: vr_j = p0[lane^j] = v_{lp^j}
            float vr1, vr2, vr3, vr4, vr5, vr6, vr7;
            asm volatile(
                "s_nop 1\n\t"
                "v_add_f32_dpp %0, %7, %8 quad_perm:[1,0,3,2] row_mask:0xf bank_mask:0xf bound_ctrl:1\n\t"
                "v_add_f32_dpp %1, %7, %8 quad_perm:[2,3,0,1] row_mask:0xf bank_mask:0xf bound_ctrl:1\n\t"
                "v_add_f32_dpp %2, %7, %8 quad_perm:[3,2,1,0] row_mask:0xf bank_mask:0xf bound_ctrl:1\n\t"
                "v_add_f32_dpp %6, %7, %8 row_half_mirror row_mask:0xf bank_mask:0xf bound_ctrl:1\n\t"
                "s_nop 1\n\t"
                "v_add_f32_dpp %5, %6, %8 quad_perm:[1,0,3,2] row_mask:0xf bank_mask:0xf bound_ctrl:1\n\t"
                "v_add_f32_dpp %4, %6, %8 quad_perm:[2,3,0,1] row_mask:0xf bank_mask:0xf bound_ctrl:1\n\t"
                "v_add_f32_dpp %3, %6, %8 quad_perm:[3,2,1,0] row_mask:0xf bank_mask:0xf bound_ctrl:1\n\t"
                : "=&v"(vr1), "=&v"(vr2), "=&v"(vr3), "=&v"(vr4),
                  "=&v"(vr5), "=&v"(vr6), "=&v"(vr7)
                : "v"(p0), "v"(fz));
            float c0 = fmaf(vr1, U0x[1], p0 * U0x[0]);
            c0 = fmaf(vr2, U0x[2], c0);
            c0 = fmaf(vr3, U0x[3], c0);
            float c1 = vr4 * U0x[4];
            c1 = fmaf(vr5, U0x[5], c1);
            c1 = fmaf(vr6, U0x[6], c1);
            c1 = fmaf(vr7, U0x[7], c1);
            float av0 = c0 + c1;
            float d0 = fmaf(vr1, U1x[1], p0 * U1x[0]);
            d0 = fmaf(vr2, U1x[2], d0);
            d0 = fmaf(vr3, U1x[3], d0);
            float d1 = vr4 * U1x[4];
            d1 = fmaf(vr5, U1x[5], d1);
            d1 = fmaf(vr6, U1x[6], d1);
            d1 = fmaf(vr7, U1x[7], d1);
            float av1 = d0 + d1;
            ha = fminf(10.0f, fmaxf(-10.0f, fmaf(a0, ha, av0) + xv.x));
            hb = fminf(10.0f, fmaxf(-10.0f, fmaf(a1, hb, av1) + xv.y));
            Hs[i * 68 + lane] = f16pk(ha, hb);
        }
        half8 Bf[4];
        #pragma unroll
        for (int kc = 0; kc < 4; ++kc)
            Bf[kc] = __builtin_bit_cast(half8,
                *(const uint4*)&Hs[row16 * 68 + kc * 16 + grp * 4]);
        #pragma unroll
        for (int ct = 0; ct < 4; ++ct) {
            f32x4 acc = {0.0f, 0.0f, 0.0f, 0.0f};
            #pragma unroll
            for (int kc = 0; kc < 4; ++kc)
                acc = __builtin_amdgcn_mfma_f32_16x16x32_f16(Af[ct][kc], Bf[kc], acc, 0, 0, 0);
            #pragma unroll
            for (int r = 0; r < 4; ++r) {
                float y = fminf(10.0f, fmaxf(-10.0f, acc[r]));
                ob[ct][(size_t)r * L_TOT + t16 * 16] = y;
            }
        }
    };

    prefetch(xqA, 0);
    #pragma unroll 1
    for (int t16 = 0; t16 < 32; t16 += 2) {
        prefetch(xqB, t16 + 1);
        do_seg(xqA, t16);
        prefetch(xqA, (t16 + 2) & 31);
        do_seg(xqB, t16 + 1);
    }
}

extern "C" void kernel_launch(void* const* d_in, const int* in_sizes, int n_in,
                              void* d_out, int out_size, void* d_ws, size_t ws_size,
                              hipStream_t stream) {
    const float* x          = (const float*)d_in[0];
    const float* g          = (const float*)d_in[1];
    const float* in_proj_w  = (const float*)d_in[2];
    const float* in_proj_b  = (const float*)d_in[3];
    const float* out_proj_w = (const float*)d_in[4];
    const float* U_base     = (const float*)d_in[5];
    const float* V_base     = (const float*)d_in[6];
    const float* a_base     = (const float*)d_in[7];
    const float* mod_uv_w   = (const float*)d_in[8];
    const float* mod_uv_b   = (const float*)d_in[9];
    const float* mod_a_w    = (const float*)d_in[10];
    const float* mod_a_b    = (const float*)d_in[11];
    const float* mod_B_w    = (const float*)d_in[12];
    const float* mod_B_b    = (const float*)d_in[13];
    const float* mod_C_w    = (const float*)d_in[14];
    const float* mod_C_b    = (const float*)d_in[15];
    const float* h0         = (const float*)d_in[16];
    float* out = (float*)d_out;
    float* ws  = (float*)d_ws;
    unsigned* xs16 = (unsigned*)(ws + WS_XS);

    hipLaunchKernelGGL(mod_kernel, dim3(4), dim3(128), 0, stream,
                       g, in_proj_w, U_base, V_base, a_base, out_proj_w,
                       mod_uv_w, mod_uv_b, mod_a_w, mod_a_b,
                       mod_B_w, mod_B_b, mod_C_w, mod_C_b, ws);
    hipLaunchKernelGGL(inproj_mfma, dim3(1024, 4), dim3(256), 0, stream,
                       x, (const unsigned*)(ws + WS_WHP), (const unsigned*)(ws + WS_WLP),
                       in_proj_b, ws, xs16);
    hipLaunchKernelGGL(scan_kernel, dim3(512), dim3(64), 0, stream,
                       xs16, ws, (const unsigned*)(ws + WS_CGP), h0, out);
}